// Round 9
// baseline (382.456 us; speedup 1.0000x reference)
//
#include <hip/hip_runtime.h>

// ChunkedLocalAttention on MI355X — round 9
// One structural change vs round 8 (passed, 351.5us): both GEMMs move from
// 256x256/8-wave/128KiB-LDS (1 block/CU, latency-bound at K=768) to
// 128x128/4-wave/BK=64/2-slot/64KiB-LDS -> 2 independent blocks/CU.
//  * Same verified XOR unit swizzle (c ^ (row&7)), same sa0/sa1 read offsets.
//  * Guide-recipe 2-phase loop: vmcnt(0)+barrier -> STG(T+1 -> s^1) ->
//    ds_read(s) -> 32 MFMA (setprio-wrapped). Race-free: s^1 readers retired
//    before the barrier that precedes the staging issue.
//  * M = 257*128 exactly: no row clamping; tile 256 == landmark rows.
//  * Epilogues = round-8 formulas reindexed (wm*64, mf 0..3).
// cvtx / lmred / cvtw / attention byte-identical to round 8.

typedef unsigned short u16;
typedef __attribute__((ext_vector_type(8))) short short8;
typedef __attribute__((ext_vector_type(4))) float f32x4;

__device__ __forceinline__ u16 f2bf(float f) {
    unsigned u = __float_as_uint(f);
    u += 0x7fffu + ((u >> 16) & 1u);   // RTNE
    return (u16)(u >> 16);
}

#define MFMA_BF16(A, B, C) __builtin_amdgcn_mfma_f32_16x16x32_bf16((A), (B), (C), 0, 0, 0)

__device__ __forceinline__ void gload16(const u16* g, const short* l) {
    __builtin_amdgcn_global_load_lds(
        (__attribute__((address_space(1))) void*)g,
        (__attribute__((address_space(3))) void*)l, 16, 0, 0);
}

// ------------------------------------------------------------- x cvt + landmarks
__global__ __launch_bounds__(256) void k_cvtx(const float* __restrict__ x,
                                              u16* __restrict__ xa,
                                              float* __restrict__ part) {
    const int g = blockIdx.x;            // 0..511
    const int t = threadIdx.x;
    const float* base = x + (size_t)g * 64 * 768;
    u16* ob = xa + (size_t)g * 64 * 768;
    float s0 = 0.f, s1 = 0.f, s2 = 0.f;
    for (int r = 0; r < 64; ++r) {
        const size_t off = (size_t)r * 768;
        const float v0 = base[off + t], v1 = base[off + t + 256], v2 = base[off + t + 512];
        s0 += v0; s1 += v1; s2 += v2;
        ob[off + t] = f2bf(v0); ob[off + t + 256] = f2bf(v1); ob[off + t + 512] = f2bf(v2);
    }
    float* p = part + (size_t)g * 768;
    p[t] = s0; p[t + 256] = s1; p[t + 512] = s2;
}

__global__ void k_lmred(const float* __restrict__ part, u16* __restrict__ xa_lm) {
    const int bl = blockIdx.x;
    const int t = threadIdx.x;
    const float* p = part + (size_t)bl * 4 * 768;
    const float inv = 1.f / 256.f;
    for (int c = t; c < 768; c += 256) {
        const float s = p[c] + p[768 + c] + p[1536 + c] + p[2304 + c];
        xa_lm[(size_t)bl * 768 + c] = f2bf(s * inv);
    }
}

__global__ void k_cvtw(const float* __restrict__ qw, const float* __restrict__ kw,
                       const float* __restrict__ vw, const float* __restrict__ ow,
                       const float* __restrict__ qb, const float* __restrict__ kb,
                       const float* __restrict__ vb,
                       u16* __restrict__ wcat, u16* __restrict__ owb,
                       float* __restrict__ bcat) {
    const int yy = blockIdx.y;
    const int i = blockIdx.x * 256 + threadIdx.x;
    if (yy == 4) {
        if (i < 768)       bcat[i] = qb[i];
        else if (i < 1536) bcat[i] = kb[i - 768];
        else if (i < 2304) bcat[i] = vb[i - 1536];
        return;
    }
    const float* src = (yy == 0) ? qw : (yy == 1) ? kw : (yy == 2) ? vw : ow;
    u16* dst = (yy == 3) ? owb : wcat + (size_t)yy * 589824;
    const float4 v = ((const float4*)src)[i];
    ushort4 o;
    o.x = f2bf(v.x); o.y = f2bf(v.y); o.z = f2bf(v.z); o.w = f2bf(v.w);
    ((ushort4*)dst)[i] = o;
}

// ------------------------------------- GEMM: 128x128, BK=64, 2 blocks/CU
template <int MODE>
__global__ __launch_bounds__(256, 2) void k_gemm(
    const u16* __restrict__ A, const u16* __restrict__ Bw, const float* __restrict__ bias,
    u16* __restrict__ qx, u16* __restrict__ ktok, u16* __restrict__ vt,
    u16* __restrict__ klm, u16* __restrict__ vlmt, float* __restrict__ outf)
{
    __shared__ short lA[2][8192];        // [slot][128r x 8 units x 8 shorts]
    __shared__ short lB[2][8192];
    const int t = threadIdx.x;           // 0..255
    const int wid = t >> 6, lane = t & 63, lr = lane & 15, lg = lane >> 4;
    const int wm = wid >> 1, wn = wid & 1;

    // bijective XCD swizzle (m204)
    const int gx = gridDim.x;
    const int nwg = gx * gridDim.y;
    const int orig = blockIdx.x + gx * blockIdx.y;
    const int qq = nwg >> 3, rr = nwg & 7, xcd = orig & 7, ii = orig >> 3;
    const int wg = (xcd < rr ? xcd * (qq + 1) : rr * (qq + 1) + (xcd - rr) * qq) + ii;
    const int m0 = (wg / gx) * 128, n0 = (wg % gx) * 128;

    // staging: pass j covers 16B units u = j*256+t; row=u>>3, col pre-swizzled
    const u16* pa[4]; const u16* pb[4];
#pragma unroll
    for (int j = 0; j < 4; ++j) {
        const int u = j * 256 + t;
        const int row = u >> 3, col = ((u & 7) ^ (row & 7)) * 8;
        pa[j] = A  + (size_t)(m0 + row) * 768 + col;
        pb[j] = Bw + (size_t)(n0 + row) * 768 + col;
    }
    const int sa0 = (lg ^ (lr & 7)) * 8;
    const int sa1 = ((4 + lg) ^ (lr & 7)) * 8;

#define STG(S, T) {                                                       \
    gload16(pa[0] + (T) * 64, &lA[S][0 * 2048 + wid * 512]);              \
    gload16(pb[0] + (T) * 64, &lB[S][0 * 2048 + wid * 512]);              \
    gload16(pa[1] + (T) * 64, &lA[S][1 * 2048 + wid * 512]);              \
    gload16(pb[1] + (T) * 64, &lB[S][1 * 2048 + wid * 512]);              \
    gload16(pa[2] + (T) * 64, &lA[S][2 * 2048 + wid * 512]);              \
    gload16(pb[2] + (T) * 64, &lB[S][2 * 2048 + wid * 512]);              \
    gload16(pa[3] + (T) * 64, &lA[S][3 * 2048 + wid * 512]);              \
    gload16(pb[3] + (T) * 64, &lB[S][3 * 2048 + wid * 512]); }

    f32x4 acc[4][4] = {};
    STG(0, 0);

#pragma unroll
    for (int T = 0; T < 12; ++T) {
        const int s = T & 1;
        asm volatile("s_waitcnt vmcnt(0)" ::: "memory");
        __builtin_amdgcn_s_barrier();
        __builtin_amdgcn_sched_barrier(0);
        if (T + 1 < 12) STG(s ^ 1, T + 1);   // latency hides under this tile's compute
        short8 aq[4][2], bq[4][2];
#pragma unroll
        for (int mf = 0; mf < 4; ++mf) {
            const int rb = (wm * 64 + mf * 16 + lr) * 64;
            aq[mf][0] = *(const short8*)&lA[s][rb + sa0];
            aq[mf][1] = *(const short8*)&lA[s][rb + sa1];
        }
#pragma unroll
        for (int nf = 0; nf < 4; ++nf) {
            const int rb = (wn * 64 + nf * 16 + lr) * 64;
            bq[nf][0] = *(const short8*)&lB[s][rb + sa0];
            bq[nf][1] = *(const short8*)&lB[s][rb + sa1];
        }
        __builtin_amdgcn_s_setprio(1);
#pragma unroll
        for (int mf = 0; mf < 4; ++mf)
#pragma unroll
            for (int nf = 0; nf < 4; ++nf)
#pragma unroll
                for (int kf = 0; kf < 2; ++kf)
                    acc[mf][nf] = MFMA_BF16(aq[mf][kf], bq[nf][kf], acc[mf][nf]);
        __builtin_amdgcn_s_setprio(0);
    }
#undef STG

    if (MODE == 0) {
        const int region = n0 / 768;         // 0=Q 1=K 2=V (uniform per block)
        if (region == 2) {
            // ---- V: packed transposed ushort4 stores direct to vt / vlmt
#pragma unroll
            for (int nf = 0; nf < 4; ++nf) {
                const int gn = n0 + wn * 64 + nf * 16 + lr;
                const float bv = bias[gn];
                const int nn = gn - 1536;
                const int h = nn >> 6, d = nn & 63;
#pragma unroll
                for (int mf = 0; mf < 4; ++mf) {
                    const int gmb = m0 + wm * 64 + mf * 16 + lg * 4;
                    ushort4 w;
                    w.x = f2bf(acc[mf][nf][0] + bv);
                    w.y = f2bf(acc[mf][nf][1] + bv);
                    w.z = f2bf(acc[mf][nf][2] + bv);
                    w.w = f2bf(acc[mf][nf][3] + bv);
                    if (gmb < 32768) {
                        const int b = gmb >> 13, ss = gmb & 8191;
                        *(ushort4*)(vt + ((size_t)(b * 12 + h) * 64 + d) * 8192 + ss) = w;
                    } else {
                        const int ii2 = gmb - 32768;
                        const int bb = ii2 >> 5, lmr = ii2 & 31;
                        *(ushort4*)(vlmt + ((size_t)(bb * 12 + h) * 64 + d) * 32 + lmr) = w;
                    }
                }
            }
        } else {
            // ---- Q/K: scalar stores (round-8 verified formulas)
            u16* dst = (region == 0) ? qx : ktok;
#pragma unroll
            for (int nf = 0; nf < 4; ++nf) {
                const int gn = n0 + wn * 64 + nf * 16 + lr;
                const int nn = gn - region * 768;
                const int h = nn >> 6, d = nn & 63;
                const float bv = bias[gn];
#pragma unroll
                for (int mf = 0; mf < 4; ++mf) {
                    const int gmb = m0 + wm * 64 + mf * 16 + lg * 4;
#pragma unroll
                    for (int r = 0; r < 4; ++r) {
                        const int gm = gmb + r;
                        const u16 val = f2bf(acc[mf][nf][r] + bv);
                        if (gm < 32768) {
                            const int b = gm >> 13, ss = gm & 8191;
                            dst[((size_t)(b * 12 + h) * 8192 + ss) * 64 + d] = val;
                        } else if (region == 1) {
                            const int ii2 = gm - 32768;
                            klm[((size_t)((ii2 >> 5) * 12 + h) * 32 + (ii2 & 31)) * 64 + d] = val;
                        }
                    }
                }
            }
        }
    } else {
#pragma unroll
        for (int nf = 0; nf < 4; ++nf) {
            const int gn = n0 + wn * 64 + nf * 16 + lr;
            const float bvv = bias[gn];
#pragma unroll
            for (int mf = 0; mf < 4; ++mf) {
                const int gmb = m0 + wm * 64 + mf * 16 + lg * 4;
#pragma unroll
                for (int r = 0; r < 4; ++r)
                    outf[(size_t)(gmb + r) * 768 + gn] = acc[mf][nf][r] + bvv;
            }
        }
    }
}

// ---------------------------------------------------------------- attention
__global__ __launch_bounds__(256) void k_attn(
    const u16* __restrict__ q, const u16* __restrict__ ktok,
    const u16* __restrict__ klm, const u16* __restrict__ vt,
    const u16* __restrict__ vlmt, u16* __restrict__ ao)
{
    __shared__ short kls[2][32 * 72];
    __shared__ short vls[2][64 * 40];
    __shared__ short pls[4][64 * 40];
    const int t = threadIdx.x, wid = t >> 6, l = t & 63, lr = l & 15, lg = l >> 4;
    const int idx = blockIdx.x;
    const int qt = idx & 1;
    const int h  = (idx >> 1) % 12;
    const int cb = (idx >> 1) / 12;
    const int c  = cb & 15, b = cb >> 4;
    const int bh = b * 12 + h;
    const int sb = c * 512 + qt * 256 + wid * 64;

    short8 qf[4][2];
#pragma unroll
    for (int mf = 0; mf < 4; ++mf)
#pragma unroll
        for (int kf = 0; kf < 2; ++kf)
            qf[mf][kf] = *(const short8*)(q + ((size_t)bh * 8192 + sb + mf * 16 + lr) * 64
                                            + kf * 32 + lg * 8);

    f32x4 O[4][4] = {};
    float lsum[4][4] = {};

    short* pw = &pls[wid][0];
    const int kn = t >> 3, kko = (t & 7) * 8;
    const int kctx = (kn < 16) ? (kn * 2) : ((kn - 16) * 2 + 1);
    const int vd = t >> 2, vco = (t & 3) * 8;

    auto kaddr = [&](int ti) -> const u16* {
        if (ti == 0) return klm + ((size_t)bh * 32 + kctx) * 64 + kko;
        return ktok + ((size_t)bh * 8192 + c * 512 + (ti - 1) * 32 + kctx) * 64 + kko;
    };
    auto vaddr = [&](int ti) -> const u16* {
        if (ti == 0) return vlmt + ((size_t)bh * 64 + vd) * 32 + vco;
        return vt + ((size_t)bh * 64 + vd) * 8192 + c * 512 + (ti - 1) * 32 + vco;
    };

    {
        const uint4 rk0 = *(const uint4*)kaddr(0);
        const uint4 rv0 = *(const uint4*)vaddr(0);
        *(uint4*)&kls[0][kn * 72 + kko] = rk0;
        *(uint4*)&vls[0][vd * 40 + vco] = rv0;
    }
    __syncthreads();

    for (int ti = 0; ti < 17; ++ti) {
        const int cur = ti & 1, nxt = cur ^ 1;
        uint4 rk, rv;
        if (ti < 16) { rk = *(const uint4*)kaddr(ti + 1); rv = *(const uint4*)vaddr(ti + 1); }

        f32x4 sc[4][2] = {};
#pragma unroll
        for (int kf = 0; kf < 2; ++kf) {
            const short8 b0 = *(const short8*)&kls[cur][(lr)      * 72 + kf * 32 + lg * 8];
            const short8 b1 = *(const short8*)&kls[cur][(16 + lr) * 72 + kf * 32 + lg * 8];
#pragma unroll
            for (int mf = 0; mf < 4; ++mf) {
                sc[mf][0] = MFMA_BF16(qf[mf][kf], b0, sc[mf][0]);
                sc[mf][1] = MFMA_BF16(qf[mf][kf], b1, sc[mf][1]);
            }
        }

#pragma unroll
        for (int mf = 0; mf < 4; ++mf) {
#pragma unroll
            for (int r = 0; r < 4; ++r) {
                const float p0 = __expf(sc[mf][0][r] * 0.125f);
                const float p1 = __expf(sc[mf][1][r] * 0.125f);
                lsum[mf][r] += p0 + p1;
                unsigned pk;
                asm("v_cvt_pk_bf16_f32 %0, %1, %2" : "=v"(pk) : "v"(p0), "v"(p1));
                const int prow = mf * 16 + lg * 4 + r;
                ((unsigned*)pw)[prow * 20 + lr] = pk;
            }
        }

        short8 vb[4];
#pragma unroll
        for (int df = 0; df < 4; ++df)
            vb[df] = *(const short8*)&vls[cur][(df * 16 + lr) * 40 + lg * 8];
#pragma unroll
        for (int mf = 0; mf < 4; ++mf) {
            const short8 pa2 = *(const short8*)&pw[(mf * 16 + lr) * 40 + lg * 8];
#pragma unroll
            for (int df = 0; df < 4; ++df)
                O[mf][df] = MFMA_BF16(pa2, vb[df], O[mf][df]);
        }

        if (ti < 16) {
            *(uint4*)&kls[nxt][kn * 72 + kko] = rk;
            *(uint4*)&vls[nxt][vd * 40 + vco] = rv;
        }
        __syncthreads();
    }

#pragma unroll
    for (int mf = 0; mf < 4; ++mf)
#pragma unroll
        for (int r = 0; r < 4; ++r) {
            float lv = lsum[mf][r];
            lv += __shfl_xor(lv, 1); lv += __shfl_xor(lv, 2);
            lv += __shfl_xor(lv, 4); lv += __shfl_xor(lv, 8);
            const float inv = 1.f / lv;
            const int srow = sb + mf * 16 + lg * 4 + r;
#pragma unroll
            for (int df = 0; df < 4; ++df)
                ao[((size_t)b * 8192 + srow) * 768 + h * 64 + df * 16 + lr] =
                    f2bf(O[mf][df][r] * inv);
        }
}

// ---------------------------------------------------------------- launch
extern "C" void kernel_launch(void* const* d_in, const int* in_sizes, int n_in,
                              void* d_out, int out_size, void* d_ws, size_t ws_size,
                              hipStream_t stream)
{
    const float* x  = (const float*)d_in[0];
    const float* qw = (const float*)d_in[1];
    const float* qb = (const float*)d_in[2];
    const float* kw = (const float*)d_in[3];
    const float* kb = (const float*)d_in[4];
    const float* vw = (const float*)d_in[5];
    const float* vb = (const float*)d_in[6];
    const float* ow = (const float*)d_in[7];
    const float* ob = (const float*)d_in[8];
    float* out = (float*)d_out;

    u16* xa     = (u16*)d_ws;                        // 32896 x 768 (+128 lm rows)
    u16* wcat   = xa + (size_t)32896 * 768;          // 2304 x 768
    u16* owb    = wcat + (size_t)2304 * 768;         // 768 x 768
    float* bcat = (float*)(owb + (size_t)768 * 768); // 2304
    u16* qx     = (u16*)(bcat + 2304);               // [b,h,s,d]
    u16* ktok   = qx   + (size_t)32768 * 768;        // [b,h,s,d]
    u16* vt     = ktok + (size_t)32768 * 768;        // [b,h,d,s]
    u16* klm    = vt + (size_t)32768 * 768;          // [b,h,l,d]
    u16* vlmt   = klm + 98304;                       // [b,h,d,l]
    float* part = (float*)(vlmt + 98304);            // 512 x 768
    u16* ao     = xa;                                // alias (xa dead after gemm<0>)

    k_cvtx<<<512, 256, 0, stream>>>(x, xa, part);
    k_lmred<<<128, 256, 0, stream>>>(part, xa + (size_t)32768 * 768);
    k_cvtw<<<dim3(576, 5), 256, 0, stream>>>(qw, kw, vw, ow, qb, kb, vb, wcat, owb, bcat);

    k_gemm<0><<<dim3(18, 257), 256, 0, stream>>>(xa, wcat, bcat,
                                                 qx, ktok, vt, klm, vlmt, nullptr);
    k_attn<<<1536, 256, 0, stream>>>(qx, ktok, klm, vt, vlmt, ao);
    k_gemm<1><<<dim3(6, 256), 256, 0, stream>>>(ao, owb, ob,
                                                nullptr, nullptr, nullptr, nullptr, nullptr, out);
}

// Round 10
// 351.550 us; speedup vs baseline: 1.0879x; 1.0879x over previous
//
#include <hip/hip_runtime.h>

// ChunkedLocalAttention on MI355X — round 10
// One change vs round 8 (passed, 351.5us): both GEMMs use 128Mx256N tile,
// 8 waves (2Mx4N, wave=64x64), BK=32, 2-slot dbuf = 48KiB LDS -> 2 blocks/CU
// (16 waves/CU, __launch_bounds__(512,4) caps VGPR at 128).
//  * Counted vmcnt(3) (0 only at last tile), 2 barriers/tile, prefetch dist 2.
//  * BK=32 swizzle: store unit cu^((row>>1)&3); read off (lg^((lr>>1)&3))*8
//    -> 2-way bank aliasing (free).  M=257*128 exactly: clamping deleted.
//  * Traffic same as round 8 (9 N-tiles in gemm<0>); epilogues = round-9
//    verified formulas (wm=wid>>2, wn=wid&3).
// cvtx / lmred / cvtw / attention byte-identical to rounds 8/9.

typedef unsigned short u16;
typedef __attribute__((ext_vector_type(8))) short short8;
typedef __attribute__((ext_vector_type(4))) float f32x4;

__device__ __forceinline__ u16 f2bf(float f) {
    unsigned u = __float_as_uint(f);
    u += 0x7fffu + ((u >> 16) & 1u);   // RTNE
    return (u16)(u >> 16);
}

#define MFMA_BF16(A, B, C) __builtin_amdgcn_mfma_f32_16x16x32_bf16((A), (B), (C), 0, 0, 0)

__device__ __forceinline__ void gload16(const u16* g, const short* l) {
    __builtin_amdgcn_global_load_lds(
        (__attribute__((address_space(1))) void*)g,
        (__attribute__((address_space(3))) void*)l, 16, 0, 0);
}

// ------------------------------------------------------------- x cvt + landmarks
__global__ __launch_bounds__(256) void k_cvtx(const float* __restrict__ x,
                                              u16* __restrict__ xa,
                                              float* __restrict__ part) {
    const int g = blockIdx.x;            // 0..511
    const int t = threadIdx.x;
    const float* base = x + (size_t)g * 64 * 768;
    u16* ob = xa + (size_t)g * 64 * 768;
    float s0 = 0.f, s1 = 0.f, s2 = 0.f;
    for (int r = 0; r < 64; ++r) {
        const size_t off = (size_t)r * 768;
        const float v0 = base[off + t], v1 = base[off + t + 256], v2 = base[off + t + 512];
        s0 += v0; s1 += v1; s2 += v2;
        ob[off + t] = f2bf(v0); ob[off + t + 256] = f2bf(v1); ob[off + t + 512] = f2bf(v2);
    }
    float* p = part + (size_t)g * 768;
    p[t] = s0; p[t + 256] = s1; p[t + 512] = s2;
}

__global__ void k_lmred(const float* __restrict__ part, u16* __restrict__ xa_lm) {
    const int bl = blockIdx.x;
    const int t = threadIdx.x;
    const float* p = part + (size_t)bl * 4 * 768;
    const float inv = 1.f / 256.f;
    for (int c = t; c < 768; c += 256) {
        const float s = p[c] + p[768 + c] + p[1536 + c] + p[2304 + c];
        xa_lm[(size_t)bl * 768 + c] = f2bf(s * inv);
    }
}

__global__ void k_cvtw(const float* __restrict__ qw, const float* __restrict__ kw,
                       const float* __restrict__ vw, const float* __restrict__ ow,
                       const float* __restrict__ qb, const float* __restrict__ kb,
                       const float* __restrict__ vb,
                       u16* __restrict__ wcat, u16* __restrict__ owb,
                       float* __restrict__ bcat) {
    const int yy = blockIdx.y;
    const int i = blockIdx.x * 256 + threadIdx.x;
    if (yy == 4) {
        if (i < 768)       bcat[i] = qb[i];
        else if (i < 1536) bcat[i] = kb[i - 768];
        else if (i < 2304) bcat[i] = vb[i - 1536];
        return;
    }
    const float* src = (yy == 0) ? qw : (yy == 1) ? kw : (yy == 2) ? vw : ow;
    u16* dst = (yy == 3) ? owb : wcat + (size_t)yy * 589824;
    const float4 v = ((const float4*)src)[i];
    ushort4 o;
    o.x = f2bf(v.x); o.y = f2bf(v.y); o.z = f2bf(v.z); o.w = f2bf(v.w);
    ((ushort4*)dst)[i] = o;
}

// ---------------------- GEMM: 128M x 256N, BK=32, 8 waves, 2 blocks/CU
template <int MODE>
__global__ __launch_bounds__(512, 4) void k_gemm(
    const u16* __restrict__ A, const u16* __restrict__ Bw, const float* __restrict__ bias,
    u16* __restrict__ qx, u16* __restrict__ ktok, u16* __restrict__ vt,
    u16* __restrict__ klm, u16* __restrict__ vlmt, float* __restrict__ outf)
{
    __shared__ short lA[2][4096];        // [slot][128r x 4 units x 8 shorts]
    __shared__ short lB[2][8192];        // [slot][256r x 4 units x 8 shorts]
    const int t = threadIdx.x;           // 0..511
    const int wid = t >> 6, lane = t & 63, lr = lane & 15, lg = lane >> 4;
    const int wm = wid >> 2, wn = wid & 3;   // 2M x 4N waves, wave = 64x64

    // bijective XCD swizzle (m204)
    const int gx = gridDim.x;
    const int nwg = gx * gridDim.y;
    const int orig = blockIdx.x + gx * blockIdx.y;
    const int qq = nwg >> 3, rr = nwg & 7, xcd = orig & 7, ii = orig >> 3;
    const int wg = (xcd < rr ? xcd * (qq + 1) : rr * (qq + 1) + (xcd - rr) * qq) + ii;
    const int m0 = (wg / gx) * 128, n0 = (wg % gx) * 256;

    // staging sources (pre-swizzled col): unit u -> row u>>2, col (u&3)^((row>>1)&3)
    const int rA = t >> 2,        cA = ((t & 3) ^ ((rA >> 1) & 3)) * 8;
    const int rB0 = t >> 2,       cB0 = cA;
    const int uB1 = 512 + t;
    const int rB1 = uB1 >> 2,     cB1 = (((uB1) & 3) ^ ((rB1 >> 1) & 3)) * 8;
    const u16* pa0 = A  + (size_t)(m0 + rA) * 768 + cA;
    const u16* pb0 = Bw + (size_t)(n0 + rB0) * 768 + cB0;
    const u16* pb1 = Bw + (size_t)(n0 + rB1) * 768 + cB1;
    // swizzled ds_read col offset (constant per lane)
    const int sa = (lg ^ ((lr >> 1) & 3)) * 8;

#define STG(S, T) {                                            \
    gload16(pa0 + (T) * 32, &lA[S][wid * 512]);                \
    gload16(pb0 + (T) * 32, &lB[S][wid * 512]);                \
    gload16(pb1 + (T) * 32, &lB[S][4096 + wid * 512]); }

    f32x4 acc[4][4] = {};
    STG(0, 0); STG(1, 1);                // 6 loads in flight

#pragma unroll
    for (int T = 0; T < 24; ++T) {
        const int s = T & 1;
        if (T < 23) asm volatile("s_waitcnt vmcnt(3)" ::: "memory");
        else        asm volatile("s_waitcnt vmcnt(0)" ::: "memory");
        __builtin_amdgcn_s_barrier();
        __builtin_amdgcn_sched_barrier(0);
        short8 aq[4], bq[4];
#pragma unroll
        for (int mf = 0; mf < 4; ++mf)
            aq[mf] = *(const short8*)&lA[s][(wm * 64 + mf * 16 + lr) * 32 + sa];
#pragma unroll
        for (int nf = 0; nf < 4; ++nf)
            bq[nf] = *(const short8*)&lB[s][(wn * 64 + nf * 16 + lr) * 32 + sa];
        asm volatile("s_waitcnt lgkmcnt(0)" ::: "memory");
        __builtin_amdgcn_sched_barrier(0);
        __builtin_amdgcn_s_barrier();    // all waves done reading slot s
        if (T + 2 < 24) STG(s, T + 2);   // refill slot s under the MFMAs
        __builtin_amdgcn_s_setprio(1);
#pragma unroll
        for (int mf = 0; mf < 4; ++mf)
#pragma unroll
            for (int nf = 0; nf < 4; ++nf)
                acc[mf][nf] = MFMA_BF16(aq[mf], bq[nf], acc[mf][nf]);
        __builtin_amdgcn_s_setprio(0);
    }
#undef STG

    if (MODE == 0) {
        const int region = n0 / 768;         // 0=Q 1=K 2=V (uniform per block)
        if (region == 2) {
            // ---- V: packed transposed ushort4 stores direct to vt / vlmt
#pragma unroll
            for (int nf = 0; nf < 4; ++nf) {
                const int gn = n0 + wn * 64 + nf * 16 + lr;
                const float bv = bias[gn];
                const int nn = gn - 1536;
                const int h = nn >> 6, d = nn & 63;
#pragma unroll
                for (int mf = 0; mf < 4; ++mf) {
                    const int gmb = m0 + wm * 64 + mf * 16 + lg * 4;
                    ushort4 w;
                    w.x = f2bf(acc[mf][nf][0] + bv);
                    w.y = f2bf(acc[mf][nf][1] + bv);
                    w.z = f2bf(acc[mf][nf][2] + bv);
                    w.w = f2bf(acc[mf][nf][3] + bv);
                    if (gmb < 32768) {
                        const int b = gmb >> 13, ss = gmb & 8191;
                        *(ushort4*)(vt + ((size_t)(b * 12 + h) * 64 + d) * 8192 + ss) = w;
                    } else {
                        const int ii2 = gmb - 32768;
                        const int bb = ii2 >> 5, lmr = ii2 & 31;
                        *(ushort4*)(vlmt + ((size_t)(bb * 12 + h) * 64 + d) * 32 + lmr) = w;
                    }
                }
            }
        } else {
            // ---- Q/K: scalar stores (round-8/9 verified formulas)
            u16* dst = (region == 0) ? qx : ktok;
#pragma unroll
            for (int nf = 0; nf < 4; ++nf) {
                const int gn = n0 + wn * 64 + nf * 16 + lr;
                const int nn = gn - region * 768;
                const int h = nn >> 6, d = nn & 63;
                const float bv = bias[gn];
#pragma unroll
                for (int mf = 0; mf < 4; ++mf) {
                    const int gmb = m0 + wm * 64 + mf * 16 + lg * 4;
#pragma unroll
                    for (int r = 0; r < 4; ++r) {
                        const int gm = gmb + r;
                        const u16 val = f2bf(acc[mf][nf][r] + bv);
                        if (gm < 32768) {
                            const int b = gm >> 13, ss = gm & 8191;
                            dst[((size_t)(b * 12 + h) * 8192 + ss) * 64 + d] = val;
                        } else if (region == 1) {
                            const int ii2 = gm - 32768;
                            klm[((size_t)((ii2 >> 5) * 12 + h) * 32 + (ii2 & 31)) * 64 + d] = val;
                        }
                    }
                }
            }
        }
    } else {
#pragma unroll
        for (int nf = 0; nf < 4; ++nf) {
            const int gn = n0 + wn * 64 + nf * 16 + lr;
            const float bvv = bias[gn];
#pragma unroll
            for (int mf = 0; mf < 4; ++mf) {
                const int gmb = m0 + wm * 64 + mf * 16 + lg * 4;
#pragma unroll
                for (int r = 0; r < 4; ++r)
                    outf[(size_t)(gmb + r) * 768 + gn] = acc[mf][nf][r] + bvv;
            }
        }
    }
}

// ---------------------------------------------------------------- attention
__global__ __launch_bounds__(256) void k_attn(
    const u16* __restrict__ q, const u16* __restrict__ ktok,
    const u16* __restrict__ klm, const u16* __restrict__ vt,
    const u16* __restrict__ vlmt, u16* __restrict__ ao)
{
    __shared__ short kls[2][32 * 72];
    __shared__ short vls[2][64 * 40];
    __shared__ short pls[4][64 * 40];
    const int t = threadIdx.x, wid = t >> 6, l = t & 63, lr = l & 15, lg = l >> 4;
    const int idx = blockIdx.x;
    const int qt = idx & 1;
    const int h  = (idx >> 1) % 12;
    const int cb = (idx >> 1) / 12;
    const int c  = cb & 15, b = cb >> 4;
    const int bh = b * 12 + h;
    const int sb = c * 512 + qt * 256 + wid * 64;

    short8 qf[4][2];
#pragma unroll
    for (int mf = 0; mf < 4; ++mf)
#pragma unroll
        for (int kf = 0; kf < 2; ++kf)
            qf[mf][kf] = *(const short8*)(q + ((size_t)bh * 8192 + sb + mf * 16 + lr) * 64
                                            + kf * 32 + lg * 8);

    f32x4 O[4][4] = {};
    float lsum[4][4] = {};

    short* pw = &pls[wid][0];
    const int kn = t >> 3, kko = (t & 7) * 8;
    const int kctx = (kn < 16) ? (kn * 2) : ((kn - 16) * 2 + 1);
    const int vd = t >> 2, vco = (t & 3) * 8;

    auto kaddr = [&](int ti) -> const u16* {
        if (ti == 0) return klm + ((size_t)bh * 32 + kctx) * 64 + kko;
        return ktok + ((size_t)bh * 8192 + c * 512 + (ti - 1) * 32 + kctx) * 64 + kko;
    };
    auto vaddr = [&](int ti) -> const u16* {
        if (ti == 0) return vlmt + ((size_t)bh * 64 + vd) * 32 + vco;
        return vt + ((size_t)bh * 64 + vd) * 8192 + c * 512 + (ti - 1) * 32 + vco;
    };

    {
        const uint4 rk0 = *(const uint4*)kaddr(0);
        const uint4 rv0 = *(const uint4*)vaddr(0);
        *(uint4*)&kls[0][kn * 72 + kko] = rk0;
        *(uint4*)&vls[0][vd * 40 + vco] = rv0;
    }
    __syncthreads();

    for (int ti = 0; ti < 17; ++ti) {
        const int cur = ti & 1, nxt = cur ^ 1;
        uint4 rk, rv;
        if (ti < 16) { rk = *(const uint4*)kaddr(ti + 1); rv = *(const uint4*)vaddr(ti + 1); }

        f32x4 sc[4][2] = {};
#pragma unroll
        for (int kf = 0; kf < 2; ++kf) {
            const short8 b0 = *(const short8*)&kls[cur][(lr)      * 72 + kf * 32 + lg * 8];
            const short8 b1 = *(const short8*)&kls[cur][(16 + lr) * 72 + kf * 32 + lg * 8];
#pragma unroll
            for (int mf = 0; mf < 4; ++mf) {
                sc[mf][0] = MFMA_BF16(qf[mf][kf], b0, sc[mf][0]);
                sc[mf][1] = MFMA_BF16(qf[mf][kf], b1, sc[mf][1]);
            }
        }

#pragma unroll
        for (int mf = 0; mf < 4; ++mf) {
#pragma unroll
            for (int r = 0; r < 4; ++r) {
                const float p0 = __expf(sc[mf][0][r] * 0.125f);
                const float p1 = __expf(sc[mf][1][r] * 0.125f);
                lsum[mf][r] += p0 + p1;
                unsigned pk;
                asm("v_cvt_pk_bf16_f32 %0, %1, %2" : "=v"(pk) : "v"(p0), "v"(p1));
                const int prow = mf * 16 + lg * 4 + r;
                ((unsigned*)pw)[prow * 20 + lr] = pk;
            }
        }

        short8 vb[4];
#pragma unroll
        for (int df = 0; df < 4; ++df)
            vb[df] = *(const short8*)&vls[cur][(df * 16 + lr) * 40 + lg * 8];
#pragma unroll
        for (int mf = 0; mf < 4; ++mf) {
            const short8 pa2 = *(const short8*)&pw[(mf * 16 + lr) * 40 + lg * 8];
#pragma unroll
            for (int df = 0; df < 4; ++df)
                O[mf][df] = MFMA_BF16(pa2, vb[df], O[mf][df]);
        }

        if (ti < 16) {
            *(uint4*)&kls[nxt][kn * 72 + kko] = rk;
            *(uint4*)&vls[nxt][vd * 40 + vco] = rv;
        }
        __syncthreads();
    }

#pragma unroll
    for (int mf = 0; mf < 4; ++mf)
#pragma unroll
        for (int r = 0; r < 4; ++r) {
            float lv = lsum[mf][r];
            lv += __shfl_xor(lv, 1); lv += __shfl_xor(lv, 2);
            lv += __shfl_xor(lv, 4); lv += __shfl_xor(lv, 8);
            const float inv = 1.f / lv;
            const int srow = sb + mf * 16 + lg * 4 + r;
#pragma unroll
            for (int df = 0; df < 4; ++df)
                ao[((size_t)b * 8192 + srow) * 768 + h * 64 + df * 16 + lr] =
                    f2bf(O[mf][df][r] * inv);
        }
}

// ---------------------------------------------------------------- launch
extern "C" void kernel_launch(void* const* d_in, const int* in_sizes, int n_in,
                              void* d_out, int out_size, void* d_ws, size_t ws_size,
                              hipStream_t stream)
{
    const float* x  = (const float*)d_in[0];
    const float* qw = (const float*)d_in[1];
    const float* qb = (const float*)d_in[2];
    const float* kw = (const float*)d_in[3];
    const float* kb = (const float*)d_in[4];
    const float* vw = (const float*)d_in[5];
    const float* vb = (const float*)d_in[6];
    const float* ow = (const float*)d_in[7];
    const float* ob = (const float*)d_in[8];
    float* out = (float*)d_out;

    u16* xa     = (u16*)d_ws;                        // 32896 x 768 (+128 lm rows)
    u16* wcat   = xa + (size_t)32896 * 768;          // 2304 x 768
    u16* owb    = wcat + (size_t)2304 * 768;         // 768 x 768
    float* bcat = (float*)(owb + (size_t)768 * 768); // 2304
    u16* qx     = (u16*)(bcat + 2304);               // [b,h,s,d]
    u16* ktok   = qx   + (size_t)32768 * 768;        // [b,h,s,d]
    u16* vt     = ktok + (size_t)32768 * 768;        // [b,h,d,s]
    u16* klm    = vt + (size_t)32768 * 768;          // [b,h,l,d]
    u16* vlmt   = klm + 98304;                       // [b,h,d,l]
    float* part = (float*)(vlmt + 98304);            // 512 x 768
    u16* ao     = xa;                                // alias (xa dead after gemm<0>)

    k_cvtx<<<512, 256, 0, stream>>>(x, xa, part);
    k_lmred<<<128, 256, 0, stream>>>(part, xa + (size_t)32768 * 768);
    k_cvtw<<<dim3(576, 5), 256, 0, stream>>>(qw, kw, vw, ow, qb, kb, vb, wcat, owb, bcat);

    k_gemm<0><<<dim3(9, 257), 512, 0, stream>>>(xa, wcat, bcat,
                                                qx, ktok, vt, klm, vlmt, nullptr);
    k_attn<<<1536, 256, 0, stream>>>(qx, ktok, klm, vt, vlmt, ao);
    k_gemm<1><<<dim3(3, 256), 512, 0, stream>>>(ao, owb, ob,
                                                nullptr, nullptr, nullptr, nullptr, nullptr, out);
}